// Round 2
// baseline (645.758 us; speedup 1.0000x reference)
//
#include <hip/hip_runtime.h>
#include <stdint.h>

typedef __bf16 bf16;
typedef bf16 bf16x8 __attribute__((ext_vector_type(8)));
typedef float f32x4 __attribute__((ext_vector_type(4)));

#define B_ROWS   65536
#define K1       784
#define FLAG_CAP 262144

// workspace layout (bytes)
#define CNT_OFF  0          // 4 B flag counter
#define LIST_OFF 4096       // 1 MB flag list
#define S1F_OFF  1052672    // 409600 B fragment-tiled sign(w1), zero-padded K->800
#define W2P_OFF  1462272    // 128x8 u32 packed sign(w2)
#define W3P_OFF  1466368    // 32x4 u32 packed sign(w3)
#define W4P_OFF  1466880    // 16 u32 packed sign(w4)
#define H1P_OFF  1470464    // 65536x8 u32 packed h1 signs -> 2 MB

// ---------------- prep: binarize/pack weights, zero flag counter ----------------
// s1f fragment-tiled layout: element e = (((step*16 + ntile)*64 + lane)*8 + j)
//   holds sign(w1)[ntile*16 + (lane&15)][step*32 + (lane>>4)*8 + j], 0 for k>=784.
__global__ __launch_bounds__(256) void prep_kernel(
    const float* __restrict__ w1, const float* __restrict__ w2,
    const float* __restrict__ w3, const float* __restrict__ w4,
    bf16* __restrict__ s1f, uint32_t* __restrict__ w2p,
    uint32_t* __restrict__ w3p, uint32_t* __restrict__ w4p,
    uint32_t* __restrict__ cnt) {
  int gid = blockIdx.x * 256 + threadIdx.x;   // 0..204799 == 25*16*64*8
  if (gid == 0) *cnt = 0u;
  {
    int j = gid & 7, l = (gid >> 3) & 63, t = (gid >> 9) & 15, s = gid >> 13;
    int fr = l & 15, fg = l >> 4;
    int n = t * 16 + fr;
    int k = s * 32 + fg * 8 + j;
    bf16 v = (bf16)0.0f;
    if (k < K1) v = (w1[n * K1 + k] >= 0.0f) ? (bf16)1.0f : (bf16)-1.0f;
    s1f[gid] = v;
  }
  if (gid < 1024) {                       // w2: 128 rows x 8 words
    int j = gid >> 3, w = gid & 7;
    uint32_t bits = 0;
    for (int i = 0; i < 32; ++i)
      bits |= (w2[j * 256 + w * 32 + i] >= 0.0f ? 1u : 0u) << i;
    w2p[gid] = bits;
  }
  if (gid < 128) {                        // w3: 32 rows x 4 words
    int j = gid >> 2, w = gid & 3;
    uint32_t bits = 0;
    for (int i = 0; i < 32; ++i)
      bits |= (w3[j * 128 + w * 32 + i] >= 0.0f ? 1u : 0u) << i;
    w3p[gid] = bits;
  }
  if (gid < 16) {                         // w4: 10 rows x 1 word (pad to 16)
    uint32_t bits = 0;
    if (gid < 10)
      for (int i = 0; i < 32; ++i)
        bits |= (w4[gid * 32 + i] >= 0.0f ? 1u : 0u) << i;
    w4p[gid] = bits;
  }
}

// ---------------- layer 1: x @ sign(w1)^T via split-bf16 MFMA ----------------
// BARRIER-FREE / LDS-FREE design. Each wave owns a 32-row x 256-col (full-N)
// output stripe -> no data shared between waves -> no LDS, no __syncthreads.
// A (x, fp32) loads straight to registers (coalesced 128B row segments),
// prefetched one step ahead (ping-pong, manual 2x unroll -> static indexing).
// hi/lo bf16 split at use: op-for-op identical numerics to verified kernel.
// B streams from L2-resident s1f in 4-frag groups (16 VGPRs).
// Grid 512 blocks = exactly 2 blocks/CU, all resident, single generation.
__global__ __launch_bounds__(256, 2) void gemm1_kernel(
    const float* __restrict__ x, const bf16* __restrict__ s1f,
    uint8_t* __restrict__ h1b, uint32_t* __restrict__ cnt,
    uint32_t* __restrict__ list) {
  const int tid = threadIdx.x;
  const int lane = tid & 63;
  const int wid = tid >> 6;
  const int fr = lane & 15, fg = lane >> 4;
  const int m0 = blockIdx.x * 128 + wid * 32;   // wave's first output row

  f32x4 acc[2][16];
#pragma unroll
  for (int i = 0; i < 2; ++i)
#pragma unroll
    for (int j = 0; j < 16; ++j) acc[i][j] = (f32x4){0.f, 0.f, 0.f, 0.f};

  // A: lane reads rows (m0 + i*16 + fr), k = t*32 + fg*8 .. +7  (two float4)
  const float* xp0 = x + (size_t)(m0 + fr) * K1 + fg * 8;
  const float* xp1 = xp0 + (size_t)16 * K1;
  // B: byte offset (t*16 + ntile)*1024 + lane*16  (coalesced 1KB per frag)
  const bf16* bp = s1f + (size_t)lane * 8;

  float4 ar[2][2][2];   // [parity][i-frag][half] raw fp32 A, ping-pong prefetch

#define LOAD_A(par_, t_)                                                       \
  {                                                                            \
    ar[par_][0][0] = *(const float4*)(xp0 + (t_) * 32);                        \
    ar[par_][0][1] = *(const float4*)(xp0 + (t_) * 32 + 4);                    \
    ar[par_][1][0] = *(const float4*)(xp1 + (t_) * 32);                        \
    ar[par_][1][1] = *(const float4*)(xp1 + (t_) * 32 + 4);                    \
  }

  // t=24 tail: k = 768 + fg*8; only fg<2 is in-bounds (k<784); rest zero.
#define LOAD_A24(par_)                                                         \
  {                                                                            \
    float4 z = make_float4(0.f, 0.f, 0.f, 0.f);                                \
    if (fg < 2) {                                                              \
      ar[par_][0][0] = *(const float4*)(xp0 + 24 * 32);                        \
      ar[par_][0][1] = *(const float4*)(xp0 + 24 * 32 + 4);                    \
      ar[par_][1][0] = *(const float4*)(xp1 + 24 * 32);                        \
      ar[par_][1][1] = *(const float4*)(xp1 + 24 * 32 + 4);                    \
    } else {                                                                   \
      ar[par_][0][0] = z; ar[par_][0][1] = z;                                  \
      ar[par_][1][0] = z; ar[par_][1][1] = z;                                  \
    }                                                                          \
  }

  // one K-step: optional prefetch (PF_: 1 normal, 2 guarded tail, 0 none),
  // hi/lo split of current A, then 4 B-groups x 16 MFMA.
#define STEP(t_, cur_, nxt_, PF_)                                              \
  {                                                                            \
    if ((PF_) == 1) LOAD_A(nxt_, (t_) + 1)                                     \
    else if ((PF_) == 2) LOAD_A24(nxt_)                                        \
    bf16x8 ah[2], al[2];                                                       \
    _Pragma("unroll") for (int i = 0; i < 2; ++i) {                            \
      float4 v0 = ar[cur_][i][0], v1 = ar[cur_][i][1];                         \
      bf16 h0 = (bf16)v0.x, h1 = (bf16)v0.y, h2 = (bf16)v0.z, h3 = (bf16)v0.w; \
      bf16 h4 = (bf16)v1.x, h5 = (bf16)v1.y, h6 = (bf16)v1.z, h7 = (bf16)v1.w; \
      bf16 l0 = (bf16)(v0.x - (float)h0), l1 = (bf16)(v0.y - (float)h1);       \
      bf16 l2 = (bf16)(v0.z - (float)h2), l3 = (bf16)(v0.w - (float)h3);       \
      bf16 l4 = (bf16)(v1.x - (float)h4), l5 = (bf16)(v1.y - (float)h5);       \
      bf16 l6 = (bf16)(v1.z - (float)h6), l7 = (bf16)(v1.w - (float)h7);       \
      ah[i] = (bf16x8){h0, h1, h2, h3, h4, h5, h6, h7};                        \
      al[i] = (bf16x8){l0, l1, l2, l3, l4, l5, l6, l7};                        \
    }                                                                          \
    _Pragma("unroll") for (int jg = 0; jg < 4; ++jg) {                         \
      bf16x8 b0 = *(const bf16x8*)(bp + ((size_t)(t_) * 16 + jg * 4 + 0) * 512);\
      bf16x8 b1 = *(const bf16x8*)(bp + ((size_t)(t_) * 16 + jg * 4 + 1) * 512);\
      bf16x8 b2 = *(const bf16x8*)(bp + ((size_t)(t_) * 16 + jg * 4 + 2) * 512);\
      bf16x8 b3 = *(const bf16x8*)(bp + ((size_t)(t_) * 16 + jg * 4 + 3) * 512);\
      _Pragma("unroll") for (int i = 0; i < 2; ++i) {                          \
        acc[i][jg * 4 + 0] = __builtin_amdgcn_mfma_f32_16x16x32_bf16(ah[i], b0, acc[i][jg * 4 + 0], 0, 0, 0); \
        acc[i][jg * 4 + 0] = __builtin_amdgcn_mfma_f32_16x16x32_bf16(al[i], b0, acc[i][jg * 4 + 0], 0, 0, 0); \
        acc[i][jg * 4 + 1] = __builtin_amdgcn_mfma_f32_16x16x32_bf16(ah[i], b1, acc[i][jg * 4 + 1], 0, 0, 0); \
        acc[i][jg * 4 + 1] = __builtin_amdgcn_mfma_f32_16x16x32_bf16(al[i], b1, acc[i][jg * 4 + 1], 0, 0, 0); \
        acc[i][jg * 4 + 2] = __builtin_amdgcn_mfma_f32_16x16x32_bf16(ah[i], b2, acc[i][jg * 4 + 2], 0, 0, 0); \
        acc[i][jg * 4 + 2] = __builtin_amdgcn_mfma_f32_16x16x32_bf16(al[i], b2, acc[i][jg * 4 + 2], 0, 0, 0); \
        acc[i][jg * 4 + 3] = __builtin_amdgcn_mfma_f32_16x16x32_bf16(ah[i], b3, acc[i][jg * 4 + 3], 0, 0, 0); \
        acc[i][jg * 4 + 3] = __builtin_amdgcn_mfma_f32_16x16x32_bf16(al[i], b3, acc[i][jg * 4 + 3], 0, 0, 0); \
      }                                                                        \
    }                                                                          \
  }

  LOAD_A(0, 0)
  for (int tt = 0; tt < 11; ++tt) {       // steps 0..21
    STEP(2 * tt,     0, 1, 1)
    STEP(2 * tt + 1, 1, 0, 1)
  }
  STEP(22, 0, 1, 1)                       // prefetch A(23)
  STEP(23, 1, 0, 2)                       // guarded prefetch A(24)
  STEP(24, 0, 0, 0)                       // tail, no prefetch

  // epilogue: pack signs via ballot; flag |v|<0.05 (ballot-aggregated atomics).
  // C/D layout: col = j*16 + (lane&15), row = m0 + i*16 + (lane>>4)*4 + reg.
#define FLAG(v_, ii_, jj_, rr_)                                                \
  {                                                                            \
    unsigned long long fb = __ballot(__builtin_fabsf(v_) < 0.05f);             \
    if (fb) {                                                                  \
      int leader = __ffsll((long long)fb) - 1;                                 \
      uint32_t base = 0;                                                       \
      if (lane == leader) base = atomicAdd(cnt, (uint32_t)__popcll(fb));       \
      base = __shfl(base, leader);                                             \
      if (__builtin_fabsf(v_) < 0.05f) {                                       \
        uint32_t pos = base + (uint32_t)__popcll(fb & ((1ull << lane) - 1ull));\
        if (pos < FLAG_CAP)                                                    \
          list[pos] = ((uint32_t)(m0 + (ii_) * 16 + fg * 4 + (rr_)) << 8) |    \
                      (uint32_t)((jj_) * 16 + fr);                             \
      }                                                                        \
    }                                                                          \
  }

#pragma unroll
  for (int i = 0; i < 2; ++i) {
#pragma unroll
    for (int r = 0; r < 4; ++r) {
      uint32_t w[8];
#pragma unroll
      for (int jp = 0; jp < 8; ++jp) {
        float v0 = acc[i][2 * jp][r];
        float v1 = acc[i][2 * jp + 1][r];
        unsigned long long s0 = __ballot(v0 >= 0.0f);
        unsigned long long s1 = __ballot(v1 >= 0.0f);
        FLAG(v0, i, 2 * jp, r)
        FLAG(v1, i, 2 * jp + 1, r)
        w[jp] = (uint32_t)((s0 >> (fg * 16)) & 0xFFFF) |
                ((uint32_t)((s1 >> (fg * 16)) & 0xFFFF) << 16);
      }
      if (fr == 0) {   // lanes 0,16,32,48: each writes its own row's 256 bits
        int m = m0 + i * 16 + fg * 4 + r;
        *(uint4*)(h1b + (size_t)m * 32)      = make_uint4(w[0], w[1], w[2], w[3]);
        *(uint4*)(h1b + (size_t)m * 32 + 16) = make_uint4(w[4], w[5], w[6], w[7]);
      }
    }
  }
}

// ---------------- cleanup: recompute flagged dots EXACTLY as the fp32 reference ----------------
// VERIFIED (absmax=0): reference = BLIS/AOCL-style sgemm, KC=512, full panels
// then remainder; one fp32 accumulator per C element, ascending k in panel;
// C = fl( seq[0,512) + seq[512,784) ).
__global__ __launch_bounds__(256) void cleanup_kernel(
    const float* __restrict__ x, const float* __restrict__ w1,
    uint32_t* __restrict__ h1p, const uint32_t* __restrict__ cnt,
    const uint32_t* __restrict__ list) {
  uint32_t n = *cnt;
  if (n > FLAG_CAP) n = FLAG_CAP;
  for (uint32_t idx = blockIdx.x * 256 + threadIdx.x; idx < n; idx += 65536) {
    uint32_t e = list[idx];
    uint32_t col = e & 255u, b = e >> 8;
    const float4* xr4 = (const float4*)(x + (size_t)b * K1);
    const float4* wr4 = (const float4*)(w1 + (size_t)col * K1);
    float t1 = 0.0f, t2 = 0.0f;
    for (int k4 = 0; k4 < 128; ++k4) {          // k in [0,512)
      float4 xv = xr4[k4], wv = wr4[k4];
      t1 += (wv.x >= 0.f) ? xv.x : -xv.x;
      t1 += (wv.y >= 0.f) ? xv.y : -xv.y;
      t1 += (wv.z >= 0.f) ? xv.z : -xv.z;
      t1 += (wv.w >= 0.f) ? xv.w : -xv.w;
    }
    for (int k4 = 128; k4 < 196; ++k4) {        // k in [512,784)
      float4 xv = xr4[k4], wv = wr4[k4];
      t2 += (wv.x >= 0.f) ? xv.x : -xv.x;
      t2 += (wv.y >= 0.f) ? xv.y : -xv.y;
      t2 += (wv.z >= 0.f) ? xv.z : -xv.z;
      t2 += (wv.w >= 0.f) ? xv.w : -xv.w;
    }
    float s = t1 + t2;   // single K-panel join at 512 (BLIS KC)
    uint32_t word = b * 8u + (col >> 5);
    uint32_t mask = 1u << (col & 31u);
    if (s >= 0.0f) atomicOr(&h1p[word], mask);
    else           atomicAnd(&h1p[word], ~mask);
  }
}

// ---------------- layers 2-4: xor/popcount, one thread per batch row ----------------
__global__ __launch_bounds__(256) void layer234_kernel(
    const uint32_t* __restrict__ h1p, const uint32_t* __restrict__ w2p,
    const uint32_t* __restrict__ w3p, const uint32_t* __restrict__ w4p,
    float* __restrict__ out) {
  __shared__ __align__(16) uint32_t lw[1168];  // [0,1024) w2p, [1024,1152) w3p, [1152,1168) w4p
  for (int i = threadIdx.x; i < 1168; i += 256) {
    uint32_t v;
    if (i < 1024) v = w2p[i];
    else if (i < 1152) v = w3p[i - 1024];
    else v = w4p[i - 1152];
    lw[i] = v;
  }
  __syncthreads();
  int b = blockIdx.x * 256 + threadIdx.x;
  const uint4* hp = (const uint4*)h1p;
  uint4 a0 = hp[(size_t)b * 2], a1 = hp[(size_t)b * 2 + 1];

  uint32_t h2w[4] = {0u, 0u, 0u, 0u};
#pragma unroll 4
  for (int j = 0; j < 128; ++j) {
    uint4 w0 = *(const uint4*)&lw[j * 8];
    uint4 w1v = *(const uint4*)&lw[j * 8 + 4];
    int t = __popc(a0.x ^ w0.x) + __popc(a0.y ^ w0.y) +
            __popc(a0.z ^ w0.z) + __popc(a0.w ^ w0.w) +
            __popc(a1.x ^ w1v.x) + __popc(a1.y ^ w1v.y) +
            __popc(a1.z ^ w1v.z) + __popc(a1.w ^ w1v.w);
    h2w[j >> 5] |= (uint32_t)(t <= 128) << (j & 31);   // dot = 256-2t >= 0
  }
  uint32_t h3 = 0u;
#pragma unroll 4
  for (int j = 0; j < 32; ++j) {
    uint4 w0 = *(const uint4*)&lw[1024 + j * 4];
    int t = __popc(h2w[0] ^ w0.x) + __popc(h2w[1] ^ w0.y) +
            __popc(h2w[2] ^ w0.z) + __popc(h2w[3] ^ w0.w);
    h3 |= (uint32_t)(t <= 64) << j;                    // dot = 128-2t >= 0
  }
  float* o = out + (size_t)b * 10;
#pragma unroll
  for (int c = 0; c < 10; ++c) {
    int t = __popc(h3 ^ lw[1152 + c]);
    o[c] = (float)(32 - 2 * t);                        // final logits, no step
  }
}

extern "C" void kernel_launch(void* const* d_in, const int* in_sizes, int n_in,
                              void* d_out, int out_size, void* d_ws, size_t ws_size,
                              hipStream_t stream) {
  const float* x  = (const float*)d_in[0];
  const float* w1 = (const float*)d_in[1];
  const float* w2 = (const float*)d_in[2];
  const float* w3 = (const float*)d_in[3];
  const float* w4 = (const float*)d_in[4];
  float* out = (float*)d_out;
  uint8_t* ws = (uint8_t*)d_ws;

  uint32_t* cnt  = (uint32_t*)(ws + CNT_OFF);
  uint32_t* list = (uint32_t*)(ws + LIST_OFF);
  bf16*     s1f  = (bf16*)(ws + S1F_OFF);
  uint32_t* w2p  = (uint32_t*)(ws + W2P_OFF);
  uint32_t* w3p  = (uint32_t*)(ws + W3P_OFF);
  uint32_t* w4p  = (uint32_t*)(ws + W4P_OFF);
  uint32_t* h1p  = (uint32_t*)(ws + H1P_OFF);

  prep_kernel<<<800, 256, 0, stream>>>(w1, w2, w3, w4, s1f, w2p, w3p, w4p, cnt);
  gemm1_kernel<<<512, 256, 0, stream>>>(x, s1f, (uint8_t*)h1p, cnt, list);
  cleanup_kernel<<<256, 256, 0, stream>>>(x, w1, h1p, cnt, list);
  layer234_kernel<<<B_ROWS / 256, 256, 0, stream>>>(h1p, w2p, w3p, w4p, out);
}

// Round 3
// 433.552 us; speedup vs baseline: 1.4895x; 1.4895x over previous
//
#include <hip/hip_runtime.h>
#include <stdint.h>

typedef __bf16 bf16;
typedef bf16 bf16x8 __attribute__((ext_vector_type(8)));
typedef float f32x4 __attribute__((ext_vector_type(4)));

#define B_ROWS   65536
#define K1       784
#define CAPW     128        // per-wave flag-list capacity (expected ~12 flags/wave)
#define NWAVES   2048       // 512 blocks x 4 waves

// workspace layout (bytes)
#define CNT_OFF  0          // 2048 u32 per-wave flag counts (8 KB)
#define LIST_OFF 8192       // 2048*128*4 B = 1 MB per-wave flag segments
#define S1F_OFF  1056768    // 409600 B fragment-tiled sign(w1), zero-padded K->800
#define W2P_OFF  1466368    // 128x8 u32 packed sign(w2)
#define W3P_OFF  1470464    // 32x4 u32 packed sign(w3)
#define W4P_OFF  1470976    // 16 u32 packed sign(w4)
#define H1P_OFF  1471488    // 65536x8 u32 packed h1 signs -> 2 MB

// ---------------- prep: binarize/pack weights ----------------
// s1f fragment-tiled layout: element e = (((step*16 + ntile)*64 + lane)*8 + j)
//   holds sign(w1)[ntile*16 + (lane&15)][step*32 + (lane>>4)*8 + j], 0 for k>=784.
__global__ __launch_bounds__(256) void prep_kernel(
    const float* __restrict__ w1, const float* __restrict__ w2,
    const float* __restrict__ w3, const float* __restrict__ w4,
    bf16* __restrict__ s1f, uint32_t* __restrict__ w2p,
    uint32_t* __restrict__ w3p, uint32_t* __restrict__ w4p) {
  int gid = blockIdx.x * 256 + threadIdx.x;   // 0..204799 == 25*16*64*8
  {
    int j = gid & 7, l = (gid >> 3) & 63, t = (gid >> 9) & 15, s = gid >> 13;
    int fr = l & 15, fg = l >> 4;
    int n = t * 16 + fr;
    int k = s * 32 + fg * 8 + j;
    bf16 v = (bf16)0.0f;
    if (k < K1) v = (w1[n * K1 + k] >= 0.0f) ? (bf16)1.0f : (bf16)-1.0f;
    s1f[gid] = v;
  }
  if (gid < 1024) {                       // w2: 128 rows x 8 words
    int j = gid >> 3, w = gid & 7;
    uint32_t bits = 0;
    for (int i = 0; i < 32; ++i)
      bits |= (w2[j * 256 + w * 32 + i] >= 0.0f ? 1u : 0u) << i;
    w2p[gid] = bits;
  }
  if (gid < 128) {                        // w3: 32 rows x 4 words
    int j = gid >> 2, w = gid & 3;
    uint32_t bits = 0;
    for (int i = 0; i < 32; ++i)
      bits |= (w3[j * 128 + w * 32 + i] >= 0.0f ? 1u : 0u) << i;
    w3p[gid] = bits;
  }
  if (gid < 16) {                         // w4: 10 rows x 1 word (pad to 16)
    uint32_t bits = 0;
    if (gid < 10)
      for (int i = 0; i < 32; ++i)
        bits |= (w4[gid * 32 + i] >= 0.0f ? 1u : 0u) << i;
    w4p[gid] = bits;
  }
}

// ---------------- layer 1: x @ sign(w1)^T via split-bf16 MFMA ----------------
// BARRIER-FREE / LDS-FREE / ATOMIC-FREE design.
// R2 post-mortem: three structurally different loops all ran ~350us because
// ~23k contended same-line atomicAdds on the single flag counter serialized at
// ~13ns each (~300us tail). Fix: ballot makes flag counts wave-uniform, so each
// wave keeps its running count in a REGISTER and appends to its own private
// list segment -> zero atomics in this kernel. K-loop byte-identical to R2.
__global__ __launch_bounds__(256, 2) void gemm1_kernel(
    const float* __restrict__ x, const bf16* __restrict__ s1f,
    uint8_t* __restrict__ h1b, uint32_t* __restrict__ cntArr,
    uint32_t* __restrict__ list) {
  const int tid = threadIdx.x;
  const int lane = tid & 63;
  const int wid = tid >> 6;
  const int fr = lane & 15, fg = lane >> 4;
  const int m0 = blockIdx.x * 128 + wid * 32;   // wave's first output row
  const int waveId = blockIdx.x * 4 + wid;

  f32x4 acc[2][16];
#pragma unroll
  for (int i = 0; i < 2; ++i)
#pragma unroll
    for (int j = 0; j < 16; ++j) acc[i][j] = (f32x4){0.f, 0.f, 0.f, 0.f};

  // A: lane reads rows (m0 + i*16 + fr), k = t*32 + fg*8 .. +7  (two float4)
  const float* xp0 = x + (size_t)(m0 + fr) * K1 + fg * 8;
  const float* xp1 = xp0 + (size_t)16 * K1;
  // B: byte offset (t*16 + ntile)*1024 + lane*16  (coalesced 1KB per frag)
  const bf16* bp = s1f + (size_t)lane * 8;

  float4 ar[2][2][2];   // [parity][i-frag][half] raw fp32 A, ping-pong prefetch

#define LOAD_A(par_, t_)                                                       \
  {                                                                            \
    ar[par_][0][0] = *(const float4*)(xp0 + (t_) * 32);                        \
    ar[par_][0][1] = *(const float4*)(xp0 + (t_) * 32 + 4);                    \
    ar[par_][1][0] = *(const float4*)(xp1 + (t_) * 32);                        \
    ar[par_][1][1] = *(const float4*)(xp1 + (t_) * 32 + 4);                    \
  }

  // t=24 tail: k = 768 + fg*8; only fg<2 is in-bounds (k<784); rest zero.
#define LOAD_A24(par_)                                                         \
  {                                                                            \
    float4 z = make_float4(0.f, 0.f, 0.f, 0.f);                                \
    if (fg < 2) {                                                              \
      ar[par_][0][0] = *(const float4*)(xp0 + 24 * 32);                        \
      ar[par_][0][1] = *(const float4*)(xp0 + 24 * 32 + 4);                    \
      ar[par_][1][0] = *(const float4*)(xp1 + 24 * 32);                        \
      ar[par_][1][1] = *(const float4*)(xp1 + 24 * 32 + 4);                    \
    } else {                                                                   \
      ar[par_][0][0] = z; ar[par_][0][1] = z;                                  \
      ar[par_][1][0] = z; ar[par_][1][1] = z;                                  \
    }                                                                          \
  }

  // one K-step: optional prefetch (PF_: 1 normal, 2 guarded tail, 0 none),
  // hi/lo split of current A, then 4 B-groups x 16 MFMA.
#define STEP(t_, cur_, nxt_, PF_)                                              \
  {                                                                            \
    if ((PF_) == 1) LOAD_A(nxt_, (t_) + 1)                                     \
    else if ((PF_) == 2) LOAD_A24(nxt_)                                        \
    bf16x8 ah[2], al[2];                                                       \
    _Pragma("unroll") for (int i = 0; i < 2; ++i) {                            \
      float4 v0 = ar[cur_][i][0], v1 = ar[cur_][i][1];                         \
      bf16 h0 = (bf16)v0.x, h1 = (bf16)v0.y, h2 = (bf16)v0.z, h3 = (bf16)v0.w; \
      bf16 h4 = (bf16)v1.x, h5 = (bf16)v1.y, h6 = (bf16)v1.z, h7 = (bf16)v1.w; \
      bf16 l0 = (bf16)(v0.x - (float)h0), l1 = (bf16)(v0.y - (float)h1);       \
      bf16 l2 = (bf16)(v0.z - (float)h2), l3 = (bf16)(v0.w - (float)h3);       \
      bf16 l4 = (bf16)(v1.x - (float)h4), l5 = (bf16)(v1.y - (float)h5);       \
      bf16 l6 = (bf16)(v1.z - (float)h6), l7 = (bf16)(v1.w - (float)h7);       \
      ah[i] = (bf16x8){h0, h1, h2, h3, h4, h5, h6, h7};                        \
      al[i] = (bf16x8){l0, l1, l2, l3, l4, l5, l6, l7};                        \
    }                                                                          \
    _Pragma("unroll") for (int jg = 0; jg < 4; ++jg) {                         \
      bf16x8 b0 = *(const bf16x8*)(bp + ((size_t)(t_) * 16 + jg * 4 + 0) * 512);\
      bf16x8 b1 = *(const bf16x8*)(bp + ((size_t)(t_) * 16 + jg * 4 + 1) * 512);\
      bf16x8 b2 = *(const bf16x8*)(bp + ((size_t)(t_) * 16 + jg * 4 + 2) * 512);\
      bf16x8 b3 = *(const bf16x8*)(bp + ((size_t)(t_) * 16 + jg * 4 + 3) * 512);\
      _Pragma("unroll") for (int i = 0; i < 2; ++i) {                          \
        acc[i][jg * 4 + 0] = __builtin_amdgcn_mfma_f32_16x16x32_bf16(ah[i], b0, acc[i][jg * 4 + 0], 0, 0, 0); \
        acc[i][jg * 4 + 0] = __builtin_amdgcn_mfma_f32_16x16x32_bf16(al[i], b0, acc[i][jg * 4 + 0], 0, 0, 0); \
        acc[i][jg * 4 + 1] = __builtin_amdgcn_mfma_f32_16x16x32_bf16(ah[i], b1, acc[i][jg * 4 + 1], 0, 0, 0); \
        acc[i][jg * 4 + 1] = __builtin_amdgcn_mfma_f32_16x16x32_bf16(al[i], b1, acc[i][jg * 4 + 1], 0, 0, 0); \
        acc[i][jg * 4 + 2] = __builtin_amdgcn_mfma_f32_16x16x32_bf16(ah[i], b2, acc[i][jg * 4 + 2], 0, 0, 0); \
        acc[i][jg * 4 + 2] = __builtin_amdgcn_mfma_f32_16x16x32_bf16(al[i], b2, acc[i][jg * 4 + 2], 0, 0, 0); \
        acc[i][jg * 4 + 3] = __builtin_amdgcn_mfma_f32_16x16x32_bf16(ah[i], b3, acc[i][jg * 4 + 3], 0, 0, 0); \
        acc[i][jg * 4 + 3] = __builtin_amdgcn_mfma_f32_16x16x32_bf16(al[i], b3, acc[i][jg * 4 + 3], 0, 0, 0); \
      }                                                                        \
    }                                                                          \
  }

  LOAD_A(0, 0)
  for (int tt = 0; tt < 11; ++tt) {       // steps 0..21
    STEP(2 * tt,     0, 1, 1)
    STEP(2 * tt + 1, 1, 0, 1)
  }
  STEP(22, 0, 1, 1)                       // prefetch A(23)
  STEP(23, 1, 0, 2)                       // guarded prefetch A(24)
  STEP(24, 0, 0, 0)                       // tail, no prefetch

  // epilogue: pack signs via ballot; flag |v|<0.05 into the wave's PRIVATE
  // list segment. fb (ballot) is wave-uniform -> wcnt stays wave-uniform in a
  // register; position = wcnt + popcount of lower flagged lanes. No atomics.
  // C/D layout: col = j*16 + (lane&15), row = m0 + i*16 + (lane>>4)*4 + reg.
  uint32_t* wlist = list + (size_t)waveId * CAPW;
  uint32_t wcnt = 0;

#define FLAG(v_, ii_, jj_, rr_)                                                \
  {                                                                            \
    unsigned long long fb = __ballot(__builtin_fabsf(v_) < 0.05f);             \
    if (fb) {                                                                  \
      if (__builtin_fabsf(v_) < 0.05f) {                                       \
        uint32_t pos = wcnt + (uint32_t)__popcll(fb & ((1ull << lane) - 1ull));\
        if (pos < CAPW)                                                        \
          wlist[pos] = ((uint32_t)(m0 + (ii_) * 16 + fg * 4 + (rr_)) << 8) |   \
                       (uint32_t)((jj_) * 16 + fr);                            \
      }                                                                        \
      wcnt += (uint32_t)__popcll(fb);                                          \
    }                                                                          \
  }

#pragma unroll
  for (int i = 0; i < 2; ++i) {
#pragma unroll
    for (int r = 0; r < 4; ++r) {
      uint32_t w[8];
#pragma unroll
      for (int jp = 0; jp < 8; ++jp) {
        float v0 = acc[i][2 * jp][r];
        float v1 = acc[i][2 * jp + 1][r];
        unsigned long long s0 = __ballot(v0 >= 0.0f);
        unsigned long long s1 = __ballot(v1 >= 0.0f);
        FLAG(v0, i, 2 * jp, r)
        FLAG(v1, i, 2 * jp + 1, r)
        w[jp] = (uint32_t)((s0 >> (fg * 16)) & 0xFFFF) |
                ((uint32_t)((s1 >> (fg * 16)) & 0xFFFF) << 16);
      }
      if (fr == 0) {   // lanes 0,16,32,48: each writes its own row's 256 bits
        int m = m0 + i * 16 + fg * 4 + r;
        *(uint4*)(h1b + (size_t)m * 32)      = make_uint4(w[0], w[1], w[2], w[3]);
        *(uint4*)(h1b + (size_t)m * 32 + 16) = make_uint4(w[4], w[5], w[6], w[7]);
      }
    }
  }

  if (lane == 0) cntArr[waveId] = (wcnt < CAPW) ? wcnt : CAPW;
}

// ---------------- cleanup: recompute flagged dots EXACTLY as the fp32 reference ----------------
// VERIFIED (absmax=0): reference = BLIS/AOCL-style sgemm, KC=512, full panels
// then remainder; one fp32 accumulator per C element, ascending k in panel;
// C = fl( seq[0,512) + seq[512,784) ).
// Now iterates per-wave list segments: slot idx -> wave idx>>7, local idx&127.
__global__ __launch_bounds__(256) void cleanup_kernel(
    const float* __restrict__ x, const float* __restrict__ w1,
    uint32_t* __restrict__ h1p, const uint32_t* __restrict__ cntArr,
    const uint32_t* __restrict__ list) {
  for (uint32_t idx = blockIdx.x * 256 + threadIdx.x; idx < NWAVES * CAPW;
       idx += 65536) {
    uint32_t w = idx >> 7, li = idx & (CAPW - 1);
    if (li >= cntArr[w]) continue;
    uint32_t e = list[idx];
    uint32_t col = e & 255u, b = e >> 8;
    const float4* xr4 = (const float4*)(x + (size_t)b * K1);
    const float4* wr4 = (const float4*)(w1 + (size_t)col * K1);
    float t1 = 0.0f, t2 = 0.0f;
    for (int k4 = 0; k4 < 128; ++k4) {          // k in [0,512)
      float4 xv = xr4[k4], wv = wr4[k4];
      t1 += (wv.x >= 0.f) ? xv.x : -xv.x;
      t1 += (wv.y >= 0.f) ? xv.y : -xv.y;
      t1 += (wv.z >= 0.f) ? xv.z : -xv.z;
      t1 += (wv.w >= 0.f) ? xv.w : -xv.w;
    }
    for (int k4 = 128; k4 < 196; ++k4) {        // k in [512,784)
      float4 xv = xr4[k4], wv = wr4[k4];
      t2 += (wv.x >= 0.f) ? xv.x : -xv.x;
      t2 += (wv.y >= 0.f) ? xv.y : -xv.y;
      t2 += (wv.z >= 0.f) ? xv.z : -xv.z;
      t2 += (wv.w >= 0.f) ? xv.w : -xv.w;
    }
    float s = t1 + t2;   // single K-panel join at 512 (BLIS KC)
    uint32_t word = b * 8u + (col >> 5);
    uint32_t mask = 1u << (col & 31u);
    if (s >= 0.0f) atomicOr(&h1p[word], mask);
    else           atomicAnd(&h1p[word], ~mask);
  }
}

// ---------------- layers 2-4: xor/popcount, one thread per batch row ----------------
__global__ __launch_bounds__(256) void layer234_kernel(
    const uint32_t* __restrict__ h1p, const uint32_t* __restrict__ w2p,
    const uint32_t* __restrict__ w3p, const uint32_t* __restrict__ w4p,
    float* __restrict__ out) {
  __shared__ __align__(16) uint32_t lw[1168];  // [0,1024) w2p, [1024,1152) w3p, [1152,1168) w4p
  for (int i = threadIdx.x; i < 1168; i += 256) {
    uint32_t v;
    if (i < 1024) v = w2p[i];
    else if (i < 1152) v = w3p[i - 1024];
    else v = w4p[i - 1152];
    lw[i] = v;
  }
  __syncthreads();
  int b = blockIdx.x * 256 + threadIdx.x;
  const uint4* hp = (const uint4*)h1p;
  uint4 a0 = hp[(size_t)b * 2], a1 = hp[(size_t)b * 2 + 1];

  uint32_t h2w[4] = {0u, 0u, 0u, 0u};
#pragma unroll 4
  for (int j = 0; j < 128; ++j) {
    uint4 w0 = *(const uint4*)&lw[j * 8];
    uint4 w1v = *(const uint4*)&lw[j * 8 + 4];
    int t = __popc(a0.x ^ w0.x) + __popc(a0.y ^ w0.y) +
            __popc(a0.z ^ w0.z) + __popc(a0.w ^ w0.w) +
            __popc(a1.x ^ w1v.x) + __popc(a1.y ^ w1v.y) +
            __popc(a1.z ^ w1v.z) + __popc(a1.w ^ w1v.w);
    h2w[j >> 5] |= (uint32_t)(t <= 128) << (j & 31);   // dot = 256-2t >= 0
  }
  uint32_t h3 = 0u;
#pragma unroll 4
  for (int j = 0; j < 32; ++j) {
    uint4 w0 = *(const uint4*)&lw[1024 + j * 4];
    int t = __popc(h2w[0] ^ w0.x) + __popc(h2w[1] ^ w0.y) +
            __popc(h2w[2] ^ w0.z) + __popc(h2w[3] ^ w0.w);
    h3 |= (uint32_t)(t <= 64) << j;                    // dot = 128-2t >= 0
  }
  float* o = out + (size_t)b * 10;
#pragma unroll
  for (int c = 0; c < 10; ++c) {
    int t = __popc(h3 ^ lw[1152 + c]);
    o[c] = (float)(32 - 2 * t);                        // final logits, no step
  }
}

extern "C" void kernel_launch(void* const* d_in, const int* in_sizes, int n_in,
                              void* d_out, int out_size, void* d_ws, size_t ws_size,
                              hipStream_t stream) {
  const float* x  = (const float*)d_in[0];
  const float* w1 = (const float*)d_in[1];
  const float* w2 = (const float*)d_in[2];
  const float* w3 = (const float*)d_in[3];
  const float* w4 = (const float*)d_in[4];
  float* out = (float*)d_out;
  uint8_t* ws = (uint8_t*)d_ws;

  uint32_t* cntArr = (uint32_t*)(ws + CNT_OFF);
  uint32_t* list   = (uint32_t*)(ws + LIST_OFF);
  bf16*     s1f    = (bf16*)(ws + S1F_OFF);
  uint32_t* w2p    = (uint32_t*)(ws + W2P_OFF);
  uint32_t* w3p    = (uint32_t*)(ws + W3P_OFF);
  uint32_t* w4p    = (uint32_t*)(ws + W4P_OFF);
  uint32_t* h1p    = (uint32_t*)(ws + H1P_OFF);

  prep_kernel<<<800, 256, 0, stream>>>(w1, w2, w3, w4, s1f, w2p, w3p, w4p);
  gemm1_kernel<<<512, 256, 0, stream>>>(x, s1f, (uint8_t*)h1p, cntArr, list);
  cleanup_kernel<<<256, 256, 0, stream>>>(x, w1, h1p, cntArr, list);
  layer234_kernel<<<B_ROWS / 256, 256, 0, stream>>>(h1p, w2p, w3p, w4p, out);
}

// Round 4
// 418.668 us; speedup vs baseline: 1.5424x; 1.0356x over previous
//
#include <hip/hip_runtime.h>
#include <stdint.h>

typedef __bf16 bf16;
typedef bf16 bf16x8 __attribute__((ext_vector_type(8)));
typedef float f32x4 __attribute__((ext_vector_type(4)));

#define B_ROWS   65536
#define K1       784
#define CAPW     128        // per-wave flag-list capacity (expected ~12 flags/wave)
#define NWAVES   2048       // 512 blocks x 4 waves

// workspace layout (bytes)
#define CNT_OFF  0          // 2048 u32 per-wave flag counts (8 KB)
#define LIST_OFF 8192       // 2048*128*4 B = 1 MB per-wave flag segments
#define S1F_OFF  1056768    // 409600 B fragment-tiled sign(w1), zero-padded K->800
#define W2P_OFF  1466368    // 128x8 u32 packed sign(w2)
#define W3P_OFF  1470464    // 32x4 u32 packed sign(w3)
#define W4P_OFF  1470976    // 16 u32 packed sign(w4)
#define H1P_OFF  1471488    // 65536x8 u32 packed h1 signs -> 2 MB

#define AS1C(p) ((const __attribute__((address_space(1))) void*)(p))
#define AS3(p)  ((__attribute__((address_space(3))) void*)(p))

// ---------------- prep: binarize/pack weights ----------------
// s1f fragment-tiled layout: element e = (((step*16 + ntile)*64 + lane)*8 + j)
//   holds sign(w1)[ntile*16 + (lane&15)][step*32 + (lane>>4)*8 + j], 0 for k>=784.
__global__ __launch_bounds__(256) void prep_kernel(
    const float* __restrict__ w1, const float* __restrict__ w2,
    const float* __restrict__ w3, const float* __restrict__ w4,
    bf16* __restrict__ s1f, uint32_t* __restrict__ w2p,
    uint32_t* __restrict__ w3p, uint32_t* __restrict__ w4p) {
  int gid = blockIdx.x * 256 + threadIdx.x;   // 0..204799 == 25*16*64*8
  {
    int j = gid & 7, l = (gid >> 3) & 63, t = (gid >> 9) & 15, s = gid >> 13;
    int fr = l & 15, fg = l >> 4;
    int n = t * 16 + fr;
    int k = s * 32 + fg * 8 + j;
    bf16 v = (bf16)0.0f;
    if (k < K1) v = (w1[n * K1 + k] >= 0.0f) ? (bf16)1.0f : (bf16)-1.0f;
    s1f[gid] = v;
  }
  if (gid < 1024) {                       // w2: 128 rows x 8 words
    int j = gid >> 3, w = gid & 7;
    uint32_t bits = 0;
    for (int i = 0; i < 32; ++i)
      bits |= (w2[j * 256 + w * 32 + i] >= 0.0f ? 1u : 0u) << i;
    w2p[gid] = bits;
  }
  if (gid < 128) {                        // w3: 32 rows x 4 words
    int j = gid >> 2, w = gid & 3;
    uint32_t bits = 0;
    for (int i = 0; i < 32; ++i)
      bits |= (w3[j * 128 + w * 32 + i] >= 0.0f ? 1u : 0u) << i;
    w3p[gid] = bits;
  }
  if (gid < 16) {                         // w4: 10 rows x 1 word (pad to 16)
    uint32_t bits = 0;
    if (gid < 10)
      for (int i = 0; i < 32; ++i)
        bits |= (w4[gid * 32 + i] >= 0.0f ? 1u : 0u) << i;
    w4p[gid] = bits;
  }
}

// ---------------- layer 1: x @ sign(w1)^T via split-bf16 MFMA ----------------
// ATOMIC-FREE (R3's win, kept). R4 change: B is SHARED through LDS.
// R3 post-mortem: each wave privately streamed the full 400KB s1f from L2
// (102 MB/XCD-L2 ~ 24us floor) and the 128-VGPR cap (128 AGPR acc under
// launch_bounds(256,2)) blocked hoisting 16 B-frags, exposing L2 latency 4x
// per step. Fix: stage the 16KB per-step B-slice once per block via
// global_load_lds (linear dest = wave-uniform base + lane*16 -- s1f's
// fragment layout matches exactly), double-buffered, ONE barrier/step,
// just-in-time ds_read_b128 -> 4x less B L2 traffic, no VGPR pressure.
// Barriers were exonerated by R0/R1/R2 tri-identical timings; atomics were
// the killer. A-path, MFMA order, epilogue byte-identical -> bit-exact.
__global__ __launch_bounds__(256, 2) void gemm1_kernel(
    const float* __restrict__ x, const bf16* __restrict__ s1f,
    uint8_t* __restrict__ h1b, uint32_t* __restrict__ cntArr,
    uint32_t* __restrict__ list) {
  __shared__ __align__(16) bf16 Bs[2][8192];   // 2 x 16KB B double-buffer

  const int tid = threadIdx.x;
  const int lane = tid & 63;
  const int wid = tid >> 6;
  const int fr = lane & 15, fg = lane >> 4;
  const int m0 = blockIdx.x * 128 + wid * 32;   // wave's first output row
  const int waveId = blockIdx.x * 4 + wid;

  f32x4 acc[2][16];
#pragma unroll
  for (int i = 0; i < 2; ++i)
#pragma unroll
    for (int j = 0; j < 16; ++j) acc[i][j] = (f32x4){0.f, 0.f, 0.f, 0.f};

  // A: lane reads rows (m0 + i*16 + fr), k = t*32 + fg*8 .. +7  (two float4)
  const float* xp0 = x + (size_t)(m0 + fr) * K1 + fg * 8;
  const float* xp1 = xp0 + (size_t)16 * K1;

  float4 ar[2][2][2];   // [parity][i-frag][half] raw fp32 A, ping-pong prefetch

  // B staging: wave wid stages frags wid*4..wid*4+3 of step t_ (1KB each).
  // Per-lane global src = base + lane*16B; HW writes LDS at dest + lane*16. 
#define STAGE_B(buf_, t_)                                                      \
  {                                                                            \
    _Pragma("unroll") for (int c = 0; c < 4; ++c)                              \
        __builtin_amdgcn_global_load_lds(                                      \
            AS1C(s1f + ((size_t)(t_) * 16 + wid * 4 + c) * 512 + lane * 8),    \
            AS3(&Bs[buf_][(wid * 4 + c) * 512]), 16, 0, 0);                    \
  }

#define LOAD_A(par_, t_)                                                       \
  {                                                                            \
    ar[par_][0][0] = *(const float4*)(xp0 + (t_) * 32);                        \
    ar[par_][0][1] = *(const float4*)(xp0 + (t_) * 32 + 4);                    \
    ar[par_][1][0] = *(const float4*)(xp1 + (t_) * 32);                        \
    ar[par_][1][1] = *(const float4*)(xp1 + (t_) * 32 + 4);                    \
  }

  // t=24 tail: k = 768 + fg*8; only fg<2 is in-bounds (k<784); rest zero.
#define LOAD_A24(par_)                                                         \
  {                                                                            \
    float4 z = make_float4(0.f, 0.f, 0.f, 0.f);                                \
    if (fg < 2) {                                                              \
      ar[par_][0][0] = *(const float4*)(xp0 + 24 * 32);                        \
      ar[par_][0][1] = *(const float4*)(xp0 + 24 * 32 + 4);                    \
      ar[par_][1][0] = *(const float4*)(xp1 + 24 * 32);                        \
      ar[par_][1][1] = *(const float4*)(xp1 + 24 * 32 + 4);                    \
    } else {                                                                   \
      ar[par_][0][0] = z; ar[par_][0][1] = z;                                  \
      ar[par_][1][0] = z; ar[par_][1][1] = z;                                  \
    }                                                                          \
  }

  // one K-step: prefetch next A (regs) + stage next B (LDS buf cur^1) while
  // doing this step's MFMAs from LDS buf cur; ONE barrier at step end drains
  // both (vmcnt+lgkmcnt) and closes the read window on buf cur.
#define STEP(t_, cur_, nxt_, PF_)                                              \
  {                                                                            \
    if ((PF_) == 1) LOAD_A(nxt_, (t_) + 1)                                     \
    else if ((PF_) == 2) LOAD_A24(nxt_)                                        \
    if ((PF_) != 0) STAGE_B((cur_) ^ 1, (t_) + 1)                              \
    bf16x8 ah[2], al[2];                                                       \
    _Pragma("unroll") for (int i = 0; i < 2; ++i) {                            \
      float4 v0 = ar[cur_][i][0], v1 = ar[cur_][i][1];                         \
      bf16 h0 = (bf16)v0.x, h1 = (bf16)v0.y, h2 = (bf16)v0.z, h3 = (bf16)v0.w; \
      bf16 h4 = (bf16)v1.x, h5 = (bf16)v1.y, h6 = (bf16)v1.z, h7 = (bf16)v1.w; \
      bf16 l0 = (bf16)(v0.x - (float)h0), l1 = (bf16)(v0.y - (float)h1);       \
      bf16 l2 = (bf16)(v0.z - (float)h2), l3 = (bf16)(v0.w - (float)h3);       \
      bf16 l4 = (bf16)(v1.x - (float)h4), l5 = (bf16)(v1.y - (float)h5);       \
      bf16 l6 = (bf16)(v1.z - (float)h6), l7 = (bf16)(v1.w - (float)h7);       \
      ah[i] = (bf16x8){h0, h1, h2, h3, h4, h5, h6, h7};                        \
      al[i] = (bf16x8){l0, l1, l2, l3, l4, l5, l6, l7};                        \
    }                                                                          \
    _Pragma("unroll") for (int jg = 0; jg < 4; ++jg) {                         \
      bf16x8 b0 = *(const bf16x8*)&Bs[cur_][(jg * 4 + 0) * 512 + lane * 8];    \
      bf16x8 b1 = *(const bf16x8*)&Bs[cur_][(jg * 4 + 1) * 512 + lane * 8];    \
      bf16x8 b2 = *(const bf16x8*)&Bs[cur_][(jg * 4 + 2) * 512 + lane * 8];    \
      bf16x8 b3 = *(const bf16x8*)&Bs[cur_][(jg * 4 + 3) * 512 + lane * 8];    \
      _Pragma("unroll") for (int i = 0; i < 2; ++i) {                          \
        acc[i][jg * 4 + 0] = __builtin_amdgcn_mfma_f32_16x16x32_bf16(ah[i], b0, acc[i][jg * 4 + 0], 0, 0, 0); \
        acc[i][jg * 4 + 0] = __builtin_amdgcn_mfma_f32_16x16x32_bf16(al[i], b0, acc[i][jg * 4 + 0], 0, 0, 0); \
        acc[i][jg * 4 + 1] = __builtin_amdgcn_mfma_f32_16x16x32_bf16(ah[i], b1, acc[i][jg * 4 + 1], 0, 0, 0); \
        acc[i][jg * 4 + 1] = __builtin_amdgcn_mfma_f32_16x16x32_bf16(al[i], b1, acc[i][jg * 4 + 1], 0, 0, 0); \
        acc[i][jg * 4 + 2] = __builtin_amdgcn_mfma_f32_16x16x32_bf16(ah[i], b2, acc[i][jg * 4 + 2], 0, 0, 0); \
        acc[i][jg * 4 + 2] = __builtin_amdgcn_mfma_f32_16x16x32_bf16(al[i], b2, acc[i][jg * 4 + 2], 0, 0, 0); \
        acc[i][jg * 4 + 3] = __builtin_amdgcn_mfma_f32_16x16x32_bf16(ah[i], b3, acc[i][jg * 4 + 3], 0, 0, 0); \
        acc[i][jg * 4 + 3] = __builtin_amdgcn_mfma_f32_16x16x32_bf16(al[i], b3, acc[i][jg * 4 + 3], 0, 0, 0); \
      }                                                                        \
    }                                                                          \
    if ((PF_) != 0) __syncthreads();                                           \
  }

  STAGE_B(0, 0)
  LOAD_A(0, 0)
  __syncthreads();   // drains stage(0) (vmcnt0) before first LDS reads

  for (int tt = 0; tt < 11; ++tt) {       // steps 0..21
    STEP(2 * tt,     0, 1, 1)
    STEP(2 * tt + 1, 1, 0, 1)
  }
  STEP(22, 0, 1, 1)                       // prefetch A(23), stage B(23)
  STEP(23, 1, 0, 2)                       // guarded prefetch A(24), stage B(24)
  STEP(24, 0, 0, 0)                       // tail, no prefetch, no barrier

  // epilogue: pack signs via ballot; flag |v|<0.05 into the wave's PRIVATE
  // list segment. fb (ballot) is wave-uniform -> wcnt stays wave-uniform in a
  // register; position = wcnt + popcount of lower flagged lanes. No atomics.
  // C/D layout: col = j*16 + (lane&15), row = m0 + i*16 + (lane>>4)*4 + reg.
  uint32_t* wlist = list + (size_t)waveId * CAPW;
  uint32_t wcnt = 0;

#define FLAG(v_, ii_, jj_, rr_)                                                \
  {                                                                            \
    unsigned long long fb = __ballot(__builtin_fabsf(v_) < 0.05f);             \
    if (fb) {                                                                  \
      if (__builtin_fabsf(v_) < 0.05f) {                                       \
        uint32_t pos = wcnt + (uint32_t)__popcll(fb & ((1ull << lane) - 1ull));\
        if (pos < CAPW)                                                        \
          wlist[pos] = ((uint32_t)(m0 + (ii_) * 16 + fg * 4 + (rr_)) << 8) |   \
                       (uint32_t)((jj_) * 16 + fr);                            \
      }                                                                        \
      wcnt += (uint32_t)__popcll(fb);                                          \
    }                                                                          \
  }

#pragma unroll
  for (int i = 0; i < 2; ++i) {
#pragma unroll
    for (int r = 0; r < 4; ++r) {
      uint32_t w[8];
#pragma unroll
      for (int jp = 0; jp < 8; ++jp) {
        float v0 = acc[i][2 * jp][r];
        float v1 = acc[i][2 * jp + 1][r];
        unsigned long long s0 = __ballot(v0 >= 0.0f);
        unsigned long long s1 = __ballot(v1 >= 0.0f);
        FLAG(v0, i, 2 * jp, r)
        FLAG(v1, i, 2 * jp + 1, r)
        w[jp] = (uint32_t)((s0 >> (fg * 16)) & 0xFFFF) |
                ((uint32_t)((s1 >> (fg * 16)) & 0xFFFF) << 16);
      }
      if (fr == 0) {   // lanes 0,16,32,48: each writes its own row's 256 bits
        int m = m0 + i * 16 + fg * 4 + r;
        *(uint4*)(h1b + (size_t)m * 32)      = make_uint4(w[0], w[1], w[2], w[3]);
        *(uint4*)(h1b + (size_t)m * 32 + 16) = make_uint4(w[4], w[5], w[6], w[7]);
      }
    }
  }

  if (lane == 0) cntArr[waveId] = (wcnt < CAPW) ? wcnt : CAPW;
}

// ---------------- cleanup: recompute flagged dots EXACTLY as the fp32 reference ----------------
// VERIFIED (absmax=0): reference = BLIS/AOCL-style sgemm, KC=512, full panels
// then remainder; one fp32 accumulator per C element, ascending k in panel;
// C = fl( seq[0,512) + seq[512,784) ).
// Iterates per-wave list segments: slot idx -> wave idx>>7, local idx&127.
__global__ __launch_bounds__(256) void cleanup_kernel(
    const float* __restrict__ x, const float* __restrict__ w1,
    uint32_t* __restrict__ h1p, const uint32_t* __restrict__ cntArr,
    const uint32_t* __restrict__ list) {
  for (uint32_t idx = blockIdx.x * 256 + threadIdx.x; idx < NWAVES * CAPW;
       idx += 65536) {
    uint32_t w = idx >> 7, li = idx & (CAPW - 1);
    if (li >= cntArr[w]) continue;
    uint32_t e = list[idx];
    uint32_t col = e & 255u, b = e >> 8;
    const float4* xr4 = (const float4*)(x + (size_t)b * K1);
    const float4* wr4 = (const float4*)(w1 + (size_t)col * K1);
    float t1 = 0.0f, t2 = 0.0f;
    for (int k4 = 0; k4 < 128; ++k4) {          // k in [0,512)
      float4 xv = xr4[k4], wv = wr4[k4];
      t1 += (wv.x >= 0.f) ? xv.x : -xv.x;
      t1 += (wv.y >= 0.f) ? xv.y : -xv.y;
      t1 += (wv.z >= 0.f) ? xv.z : -xv.z;
      t1 += (wv.w >= 0.f) ? xv.w : -xv.w;
    }
    for (int k4 = 128; k4 < 196; ++k4) {        // k in [512,784)
      float4 xv = xr4[k4], wv = wr4[k4];
      t2 += (wv.x >= 0.f) ? xv.x : -xv.x;
      t2 += (wv.y >= 0.f) ? xv.y : -xv.y;
      t2 += (wv.z >= 0.f) ? xv.z : -xv.z;
      t2 += (wv.w >= 0.f) ? xv.w : -xv.w;
    }
    float s = t1 + t2;   // single K-panel join at 512 (BLIS KC)
    uint32_t word = b * 8u + (col >> 5);
    uint32_t mask = 1u << (col & 31u);
    if (s >= 0.0f) atomicOr(&h1p[word], mask);
    else           atomicAnd(&h1p[word], ~mask);
  }
}

// ---------------- layers 2-4: xor/popcount, one thread per batch row ----------------
__global__ __launch_bounds__(256) void layer234_kernel(
    const uint32_t* __restrict__ h1p, const uint32_t* __restrict__ w2p,
    const uint32_t* __restrict__ w3p, const uint32_t* __restrict__ w4p,
    float* __restrict__ out) {
  __shared__ __align__(16) uint32_t lw[1168];  // [0,1024) w2p, [1024,1152) w3p, [1152,1168) w4p
  for (int i = threadIdx.x; i < 1168; i += 256) {
    uint32_t v;
    if (i < 1024) v = w2p[i];
    else if (i < 1152) v = w3p[i - 1024];
    else v = w4p[i - 1152];
    lw[i] = v;
  }
  __syncthreads();
  int b = blockIdx.x * 256 + threadIdx.x;
  const uint4* hp = (const uint4*)h1p;
  uint4 a0 = hp[(size_t)b * 2], a1 = hp[(size_t)b * 2 + 1];

  uint32_t h2w[4] = {0u, 0u, 0u, 0u};
#pragma unroll 4
  for (int j = 0; j < 128; ++j) {
    uint4 w0 = *(const uint4*)&lw[j * 8];
    uint4 w1v = *(const uint4*)&lw[j * 8 + 4];
    int t = __popc(a0.x ^ w0.x) + __popc(a0.y ^ w0.y) +
            __popc(a0.z ^ w0.z) + __popc(a0.w ^ w0.w) +
            __popc(a1.x ^ w1v.x) + __popc(a1.y ^ w1v.y) +
            __popc(a1.z ^ w1v.z) + __popc(a1.w ^ w1v.w);
    h2w[j >> 5] |= (uint32_t)(t <= 128) << (j & 31);   // dot = 256-2t >= 0
  }
  uint32_t h3 = 0u;
#pragma unroll 4
  for (int j = 0; j < 32; ++j) {
    uint4 w0 = *(const uint4*)&lw[1024 + j * 4];
    int t = __popc(h2w[0] ^ w0.x) + __popc(h2w[1] ^ w0.y) +
            __popc(h2w[2] ^ w0.z) + __popc(h2w[3] ^ w0.w);
    h3 |= (uint32_t)(t <= 64) << j;                    // dot = 128-2t >= 0
  }
  float* o = out + (size_t)b * 10;
#pragma unroll
  for (int c = 0; c < 10; ++c) {
    int t = __popc(h3 ^ lw[1152 + c]);
    o[c] = (float)(32 - 2 * t);                        // final logits, no step
  }
}

extern "C" void kernel_launch(void* const* d_in, const int* in_sizes, int n_in,
                              void* d_out, int out_size, void* d_ws, size_t ws_size,
                              hipStream_t stream) {
  const float* x  = (const float*)d_in[0];
  const float* w1 = (const float*)d_in[1];
  const float* w2 = (const float*)d_in[2];
  const float* w3 = (const float*)d_in[3];
  const float* w4 = (const float*)d_in[4];
  float* out = (float*)d_out;
  uint8_t* ws = (uint8_t*)d_ws;

  uint32_t* cntArr = (uint32_t*)(ws + CNT_OFF);
  uint32_t* list   = (uint32_t*)(ws + LIST_OFF);
  bf16*     s1f    = (bf16*)(ws + S1F_OFF);
  uint32_t* w2p    = (uint32_t*)(ws + W2P_OFF);
  uint32_t* w3p    = (uint32_t*)(ws + W3P_OFF);
  uint32_t* w4p    = (uint32_t*)(ws + W4P_OFF);
  uint32_t* h1p    = (uint32_t*)(ws + H1P_OFF);

  prep_kernel<<<800, 256, 0, stream>>>(w1, w2, w3, w4, s1f, w2p, w3p, w4p);
  gemm1_kernel<<<512, 256, 0, stream>>>(x, s1f, (uint8_t*)h1p, cntArr, list);
  cleanup_kernel<<<256, 256, 0, stream>>>(x, w1, h1p, cntArr, list);
  layer234_kernel<<<B_ROWS / 256, 256, 0, stream>>>(h1p, w2p, w3p, w4p, out);
}